// Round 7
// baseline (156.040 us; speedup 1.0000x reference)
//
#include <hip/hip_runtime.h>
#include <hip/hip_bf16.h>
#include <math.h>

#define BB 4
#define CC 256
#define DKK 32
#define NN 4096
// 1/sqrt(32) * log2(e) — folded into q at QKV epilogue; attention uses raw
// v_exp_f32 (2^x): removes 32 v_mul/iter/wave from the VALU pipe.
#define QSCALE2 0.25503489022324213f

typedef __attribute__((ext_vector_type(8))) __bf16 bf16x8;
typedef __attribute__((ext_vector_type(4))) __bf16 bf16x4;
typedef __attribute__((ext_vector_type(4))) float f32x4;
typedef __attribute__((ext_vector_type(16))) float f32x16;

// ---------------------------------------------------------------------------
// Kernel 1 (fused): QKV projection reading x/W fp32 directly.
// Block: 32 n x 320 o; wave w -> o 80w..80w+79. Grid 128 x B.
// Outputs: q,k (B,N,32) bf16 (q pre-scaled by QSCALE2); V tiled for 32x32
// MFMA A-frags: [b][chunk n/32][ct c/32][kb (n%32)/16][c%32][n%16].
// ---------------------------------------------------------------------------
#define XROW 264   // LDS row stride (bf16 elems) for x-tile: 528B rows

__global__ __launch_bounds__(256) void qkv2_kernel(
    const float* __restrict__ x,
    const float* __restrict__ Wq, const float* __restrict__ Wk,
    const float* __restrict__ Wv,
    const float* __restrict__ bq, const float* __restrict__ bk,
    const float* __restrict__ bv,
    __bf16* __restrict__ qws, __bf16* __restrict__ kws, __bf16* __restrict__ vws)
{
    // overlay: xs (32 x XROW bf16, 16896B) for the GEMM; scr (64x33 f32,
    // 8448B) for the q/k epilogue transpose (used strictly after xs).
    __shared__ __align__(16) unsigned char smemB[32 * XROW * 2];
    __bf16* xs = (__bf16*)smemB;
    float (*scr)[33] = (float (*)[33])smemB;

    const int tid = threadIdx.x;
    const int w   = tid >> 6;
    const int l   = tid & 63;
    const int l15 = l & 15;
    const int lq  = l >> 4;
    const int n0  = blockIdx.x * 32;
    const int b   = blockIdx.y;

    // ---- stage x tile: read fp32 (coalesced 128B/row-segment), write
    //      transposed bf16 into LDS: xs[n][c] ----
    {
        const int cl = tid >> 3;          // 0..31: c within round
        const int nf = (tid & 7) * 4;     // 0..28
#pragma unroll
        for (int p = 0; p < 8; p++) {
            int c = p * 32 + cl;
            float4 v = *(const float4*)&x[((size_t)(b * CC + c)) * NN + n0 + nf];
            xs[(nf + 0) * XROW + c] = (__bf16)v.x;
            xs[(nf + 1) * XROW + c] = (__bf16)v.y;
            xs[(nf + 2) * XROW + c] = (__bf16)v.z;
            xs[(nf + 3) * XROW + c] = (__bf16)v.w;
        }
    }

    // per-(w,ot) W row pointers: o = 80w+16ot -> {Wq,Wk,Wv} row base + l15
    const float* wrow[5];
#pragma unroll
    for (int ot = 0; ot < 5; ot++) {
        int ob = 80 * w + ot * 16;
        const float* mat; int r0;
        if (ob < 32)      { mat = Wq; r0 = ob; }
        else if (ob < 64) { mat = Wk; r0 = ob - 32; }
        else              { mat = Wv; r0 = ob - 64; }
        wrow[ot] = mat + (size_t)(r0 + l15) * CC + lq * 8;
    }

    __syncthreads();

    const f32x4 zf = {0.f, 0.f, 0.f, 0.f};
    f32x4 acc[5][2];
#pragma unroll
    for (int i = 0; i < 5; i++)
#pragma unroll
        for (int j = 0; j < 2; j++) acc[i][j] = zf;

    const __bf16* xls = &xs[l15 * XROW + lq * 8];

    bf16x8 bcur[2], acur[5], bnxt[2], anxt[5];
#pragma unroll
    for (int nt = 0; nt < 2; nt++) bcur[nt] = *(const bf16x8*)(xls + nt * 16 * XROW);
#pragma unroll
    for (int ot = 0; ot < 5; ot++) {
        f32x4 a0 = *(const f32x4*)(wrow[ot]);
        f32x4 a1 = *(const f32x4*)(wrow[ot] + 4);
        bf16x8 af;
#pragma unroll
        for (int j = 0; j < 4; j++) { af[j] = (__bf16)a0[j]; af[4 + j] = (__bf16)a1[j]; }
        acur[ot] = af;
    }

#pragma unroll
    for (int ks = 0; ks < 8; ks++) {
        if (ks < 7) {
#pragma unroll
            for (int nt = 0; nt < 2; nt++)
                bnxt[nt] = *(const bf16x8*)(xls + nt * 16 * XROW + (ks + 1) * 32);
#pragma unroll
            for (int ot = 0; ot < 5; ot++) {
                f32x4 a0 = *(const f32x4*)(wrow[ot] + (ks + 1) * 32);
                f32x4 a1 = *(const f32x4*)(wrow[ot] + (ks + 1) * 32 + 4);
                bf16x8 af;
#pragma unroll
                for (int j = 0; j < 4; j++) { af[j] = (__bf16)a0[j]; af[4 + j] = (__bf16)a1[j]; }
                anxt[ot] = af;
            }
        }
#pragma unroll
        for (int ot = 0; ot < 5; ot++)
#pragma unroll
            for (int nt = 0; nt < 2; nt++)
                acc[ot][nt] = __builtin_amdgcn_mfma_f32_16x16x32_bf16(acur[ot], bcur[nt], acc[ot][nt], 0, 0, 0);
        if (ks < 7) {
#pragma unroll
            for (int nt = 0; nt < 2; nt++) bcur[nt] = bnxt[nt];
#pragma unroll
            for (int ot = 0; ot < 5; ot++) acur[ot] = anxt[ot];
        }
    }

    __syncthreads();   // all xs reads complete before scr overlays the LDS

    // epilogue: D row o = 80w + ot*16 + lq*4 + r, col n = nt*16 + l15
    // V store layout: vchunk[ct*1024 + kb*512 + (c&31)*16 + (n&15)]
    __bf16* vchunk = vws + (size_t)b * CC * NN + (size_t)(n0 >> 5) * 8192;
#pragma unroll
    for (int ot = 0; ot < 5; ot++) {
        int ob = 80 * w + ot * 16;
#pragma unroll
        for (int nt = 0; nt < 2; nt++) {
#pragma unroll
            for (int r = 0; r < 4; r++) {
                int o = ob + lq * 4 + r;
                int n = nt * 16 + l15;
                float val = acc[ot][nt][r];
                if (ob >= 64) {
                    int c  = o - 64;
                    int ct = c >> 5, c5 = c & 31;
                    vchunk[ct * 1024 + nt * 512 + c5 * 16 + l15] =
                        (__bf16)(val + bv[c]);
                } else if (ob < 32) {
                    scr[o][n] = (val + bq[o]) * QSCALE2;
                } else {
                    scr[o][n] = val + bk[o - 32];
                }
            }
        }
    }
    __syncthreads();
    {
        int n  = tid >> 3;            // 0..31
        int d0 = (tid & 7) * 4;       // 0..28
        bf16x4 qv, kv;
#pragma unroll
        for (int j = 0; j < 4; j++) {
            qv[j] = (__bf16)scr[d0 + j][n];
            kv[j] = (__bf16)scr[32 + d0 + j][n];
        }
        size_t base = ((size_t)b * NN + n0 + n) * DKK + d0;
        *(bf16x4*)&qws[base] = qv;
        *(bf16x4*)&kws[base] = kv;
    }
}

// ---------------------------------------------------------------------------
// Kernel 2: flash attention — 32x32 MFMA, ZERO-LDS main loop.
// Round-6 delta: P never touches LDS. The 32x32 KQ C-layout gives lane
// (m31,hi) the n-values {(g*8)+4hi+t}; the PV B-frag needs n=kk*16+hi*8+j =
// own packed group ∪ same group of lane^32 — exactly one permlane32_swap
// per packed u32 pair (T12). Semantics audit: v_permlane32_swap_b32 swaps
// vdst lanes 32-63 with vsrc lanes 0-31; with a=g[2kk], b=g[2kk+1]:
// ret0 = [own g2kk | partner g2kk+1], ret1 = [partner g2kk | own g2kk+1]
// = B-frag words {wi, 2+wi} for both halves uniformly. 8 swaps/iter replace
// 8 ds_write + 8 ds_read + lgkmcnt waits + double-buffer; the loop is pure
// register dataflow, so PV(ic) [MFMA pipe] and KQ/exp(ic+1) [VALU pipe]
// can overlap across the unroll-2 boundary. acc = 128 AGPR; VGPR <=128.
// ---------------------------------------------------------------------------
#define MST 68                     // O-reduce row stride (dwords)

__global__ __launch_bounds__(256, 2) void attn_kernel(
    const __bf16* __restrict__ qb, const __bf16* __restrict__ kb,
    const __bf16* __restrict__ vt, const float* __restrict__ x,
    float* __restrict__ out)
{
    // [0, 34816)       Ored (epilogue): 4 waves x 32 x MST fp32
    // [34816, 35840)   Ls[4][64]
    // [35840, 36096)   Linv[64]
    __shared__ __align__(16) unsigned char smem[36096];
    const int tid = threadIdx.x;
    const int w   = tid >> 6;
    const int l   = tid & 63;
    const int m31 = l & 31;           // MFMA col lane (m / A-row)
    const int hi  = l >> 5;           // k-half lane
    float* Ls   = (float*)(smem + 34816);
    float* Linv = (float*)(smem + 35840);

    // XCD swizzle: batch pinned to an XCD pair -> K/V/Q stay L2-resident
    const int beta = blockIdx.x;
    const int b    = (beta >> 1) & 3;
    const int ch   = (beta >> 3) & 1;                        // c-half
    const int mt64 = ((beta >> 4) << 1) | (beta & 1);        // 0..63
    const int m0   = mt64 * 64;

    const __bf16* qbb = qb + (size_t)b * NN * DKK;
    const __bf16* kbb = kb + (size_t)b * NN * DKK;
    const __bf16* vtb = vt + (size_t)b * CC * NN;

    // Q B-frags: qa[mt][kk]: Q[m0+mt*32+m31][kk*16 + hi*8 + j]
    bf16x8 qa[2][2];
#pragma unroll
    for (int mt = 0; mt < 2; mt++)
#pragma unroll
        for (int kk = 0; kk < 2; kk++)
            qa[mt][kk] = *(const bf16x8*)(qbb + (size_t)(m0 + mt * 32 + m31) * DKK + kk * 16 + hi * 8);

    // K A-frag strip: K[w*32 + m31 + 128*ic][hi*8 + j (+16 for kA1)]
    const __bf16* kstrip = kbb + (size_t)(w * 32 + m31) * DKK + hi * 8;
    // V A-frag strip: tile (chunk=ic*4+w, ct, kb), lane (c=m31, n=hi*8+j)
    const __bf16* vstrip = vtb + (size_t)w * 8192 + (size_t)ch * 4096
                               + m31 * 16 + hi * 8;

    const f32x16 zf16 = {0.f,0.f,0.f,0.f,0.f,0.f,0.f,0.f,
                         0.f,0.f,0.f,0.f,0.f,0.f,0.f,0.f};
    f32x16 acc[4][2];                 // [ct][mt] = 128 AGPR
#pragma unroll
    for (int ct = 0; ct < 4; ct++)
#pragma unroll
        for (int mt = 0; mt < 2; mt++) acc[ct][mt] = zf16;
    float lacc[2] = {0.f, 0.f};

    // KQ + exp + in-register P assembly.
    // e reg g*4+t -> n = g*8 + 4*hi + t. Pack group g to 2 u32; swap
    // (g_even, g_odd) across the hi halves: result = pf[mt][g>>1].
    union PU { unsigned u[4]; bf16x8 v; };
    auto kq_pack = [&](bf16x8 kA0, bf16x8 kA1, bf16x8 (&pf)[2][2]) {
#pragma unroll
        for (int mt = 0; mt < 2; mt++) {
            f32x16 e = __builtin_amdgcn_mfma_f32_32x32x16_bf16(kA0, qa[mt][0], zf16, 0, 0, 0);
            e = __builtin_amdgcn_mfma_f32_32x32x16_bf16(kA1, qa[mt][1], e, 0, 0, 0);
            float s = 0.f;
            unsigned g[4][2];
#pragma unroll
            for (int gi = 0; gi < 4; gi++) {
                bf16x4 pb;
#pragma unroll
                for (int t = 0; t < 4; t++) {
                    float v = __builtin_amdgcn_exp2f(e[4 * gi + t]);
                    s += v; pb[t] = (__bf16)v;
                }
                PU tu; *(bf16x4*)tu.u = pb;
                g[gi][0] = tu.u[0]; g[gi][1] = tu.u[1];
            }
            lacc[mt] += s;
#pragma unroll
            for (int kk = 0; kk < 2; kk++) {
                PU r;
#pragma unroll
                for (int wi = 0; wi < 2; wi++) {
                    auto sw = __builtin_amdgcn_permlane32_swap(
                        (int)g[kk * 2][wi], (int)g[kk * 2 + 1][wi], false, false);
                    r.u[wi]     = (unsigned)sw[0];
                    r.u[2 + wi] = (unsigned)sw[1];
                }
                pf[mt][kk] = r.v;
            }
        }
    };

    // ---- main loop: zero barriers, zero LDS, purely intra-wave ----
    bf16x8 kA0 = *(const bf16x8*)kstrip;
    bf16x8 kA1 = *(const bf16x8*)(kstrip + 16);
#pragma unroll 2
    for (int ic = 0; ic < 32; ic++) {
        const __bf16* vch = vstrip + (size_t)ic * 32768;

        // V kb0 group in flight early (KQ/exp covers its latency)
        bf16x8 vA[4];
#pragma unroll
        for (int ct = 0; ct < 4; ct++)
            vA[ct] = *(const bf16x8*)(vch + ct * 1024);

        // KQ(ic) -> P in registers
        bf16x8 pf[2][2];
        kq_pack(kA0, kA1, pf);

        // prefetch k(ic+1) (ic=31 reads into adjacent ws region — unused)
        kA0 = *(const bf16x8*)(kstrip + (size_t)(ic + 1) * 128 * DKK);
        kA1 = *(const bf16x8*)(kstrip + (size_t)(ic + 1) * 128 * DKK + 16);

        // V kb1 group
        bf16x8 vB[4];
#pragma unroll
        for (int ct = 0; ct < 4; ct++)
            vB[ct] = *(const bf16x8*)(vch + ct * 1024 + 512);

        // PV(ic): 8 tiles x 2 chained k-halves
        __builtin_amdgcn_s_setprio(1);
#pragma unroll
        for (int ct = 0; ct < 4; ct++)
#pragma unroll
            for (int mt = 0; mt < 2; mt++) {
                acc[ct][mt] = __builtin_amdgcn_mfma_f32_32x32x16_bf16(vA[ct], pf[mt][0], acc[ct][mt], 0, 0, 0);
                acc[ct][mt] = __builtin_amdgcn_mfma_f32_32x32x16_bf16(vB[ct], pf[mt][1], acc[ct][mt], 0, 0, 0);
            }
        __builtin_amdgcn_s_setprio(0);
    }

    // ---- l: intra-wave reduce (lanes l and l^32 share m), publish ----
#pragma unroll
    for (int mt = 0; mt < 2; mt++) lacc[mt] += __shfl_xor(lacc[mt], 32, 64);
    if (hi == 0) {
#pragma unroll
        for (int mt = 0; mt < 2; mt++) Ls[w * 64 + mt * 32 + m31] = lacc[mt];
    }
    __syncthreads();
    if (tid < 64)
        Linv[tid] = 1.0f / (Ls[tid] + Ls[64 + tid] + Ls[128 + tid] + Ls[192 + tid]);

    // ---- epilogue: cross-wave O reduce, one 32-c quarter per ct ----
    // acc[ct][mt][reg]: c = ch*128 + ct*32 + crow, crow=(reg&3)+8(reg>>2)+4hi;
    // m = mt*32 + m31.
    float* Ored = (float*)smem + w * (32 * MST);
#pragma unroll
    for (int q = 0; q < 4; q++) {
        if (q > 0) __syncthreads();       // prior quarter's reads done
#pragma unroll
        for (int mt = 0; mt < 2; mt++)
#pragma unroll
            for (int reg = 0; reg < 16; reg++) {
                int crow = (reg & 3) + 8 * (reg >> 2) + 4 * hi;
                Ored[crow * MST + mt * 32 + m31] = acc[q][mt][reg];
            }
        __syncthreads();
        // sum 4 wave-partials, normalize, residual, store
        const int cl  = tid >> 3;         // 0..31 (c within quarter)
        const int mi0 = (tid & 7) * 8;    // m offset
        const float* Ob = (const float*)smem + cl * MST;
#pragma unroll
        for (int j = 0; j < 2; j++) {
            int mi = mi0 + 4 * j;
            f32x4 s = *(const f32x4*)&Ob[mi];
            s = s + *(const f32x4*)&Ob[1 * (32 * MST) + mi];
            s = s + *(const f32x4*)&Ob[2 * (32 * MST) + mi];
            s = s + *(const f32x4*)&Ob[3 * (32 * MST) + mi];
            f32x4 li = *(const f32x4*)&Linv[mi];
            int c = ch * 128 + q * 32 + cl;
            size_t gi = ((size_t)(b * CC + c)) * NN + m0 + mi;
            f32x4 xr = *(const f32x4*)&x[gi];
            *(f32x4*)&out[gi] = s * li + xr;
        }
    }
}

extern "C" void kernel_launch(void* const* d_in, const int* in_sizes, int n_in,
                              void* d_out, int out_size, void* d_ws, size_t ws_size,
                              hipStream_t stream) {
    const float* x  = (const float*)d_in[0];
    const float* Wq = (const float*)d_in[1];
    const float* bq = (const float*)d_in[2];
    const float* Wk = (const float*)d_in[3];
    const float* bk = (const float*)d_in[4];
    const float* Wv = (const float*)d_in[5];
    const float* bv = (const float*)d_in[6];
    float* out = (float*)d_out;

    __bf16* qws = (__bf16*)d_ws;                       // B*N*32
    __bf16* kws = qws + (size_t)BB * NN * DKK;         // B*N*32
    __bf16* vws = kws + (size_t)BB * NN * DKK;         // B*C*N (tiled)

    qkv2_kernel<<<dim3(128, BB), 256, 0, stream>>>(x, Wq, Wk, Wv, bq, bk, bv,
                                                   qws, kws, vws);
    attn_kernel<<<dim3(512), 256, 0, stream>>>(qws, kws, vws, x, out);
}

// Round 8
// 151.541 us; speedup vs baseline: 1.0297x; 1.0297x over previous
//
#include <hip/hip_runtime.h>
#include <hip/hip_bf16.h>
#include <math.h>

#define BB 4
#define CC 256
#define DKK 32
#define NN 4096
// 1/sqrt(32) * log2(e) — folded into q at QKV epilogue; attention uses raw
// v_exp_f32 (2^x): removes 32 v_mul/iter/wave from the VALU pipe.
#define QSCALE2 0.25503489022324213f

typedef __attribute__((ext_vector_type(8))) __bf16 bf16x8;
typedef __attribute__((ext_vector_type(4))) __bf16 bf16x4;
typedef __attribute__((ext_vector_type(4))) float f32x4;
typedef __attribute__((ext_vector_type(16))) float f32x16;

// ---------------------------------------------------------------------------
// Kernel 1 (fused): QKV projection reading x/W fp32 directly.
// Block: 32 n x 320 o; wave w -> o 80w..80w+79. Grid 128 x B.
// Outputs: q,k (B,N,32) bf16 (q pre-scaled by QSCALE2); V tiled for 32x32
// MFMA A-frags: [b][chunk n/32][ct c/32][kb (n%32)/16][c%32][n%16].
// ---------------------------------------------------------------------------
#define XROW 264   // LDS row stride (bf16 elems) for x-tile: 528B rows

__global__ __launch_bounds__(256) void qkv2_kernel(
    const float* __restrict__ x,
    const float* __restrict__ Wq, const float* __restrict__ Wk,
    const float* __restrict__ Wv,
    const float* __restrict__ bq, const float* __restrict__ bk,
    const float* __restrict__ bv,
    __bf16* __restrict__ qws, __bf16* __restrict__ kws, __bf16* __restrict__ vws)
{
    // overlay: xs (32 x XROW bf16, 16896B) for the GEMM; scr (64x33 f32,
    // 8448B) for the q/k epilogue transpose (used strictly after xs).
    __shared__ __align__(16) unsigned char smemB[32 * XROW * 2];
    __bf16* xs = (__bf16*)smemB;
    float (*scr)[33] = (float (*)[33])smemB;

    const int tid = threadIdx.x;
    const int w   = tid >> 6;
    const int l   = tid & 63;
    const int l15 = l & 15;
    const int lq  = l >> 4;
    const int n0  = blockIdx.x * 32;
    const int b   = blockIdx.y;

    // ---- stage x tile: read fp32 (coalesced 128B/row-segment), write
    //      transposed bf16 into LDS: xs[n][c] ----
    {
        const int cl = tid >> 3;          // 0..31: c within round
        const int nf = (tid & 7) * 4;     // 0..28
#pragma unroll
        for (int p = 0; p < 8; p++) {
            int c = p * 32 + cl;
            float4 v = *(const float4*)&x[((size_t)(b * CC + c)) * NN + n0 + nf];
            xs[(nf + 0) * XROW + c] = (__bf16)v.x;
            xs[(nf + 1) * XROW + c] = (__bf16)v.y;
            xs[(nf + 2) * XROW + c] = (__bf16)v.z;
            xs[(nf + 3) * XROW + c] = (__bf16)v.w;
        }
    }

    // per-(w,ot) W row pointers: o = 80w+16ot -> {Wq,Wk,Wv} row base + l15
    const float* wrow[5];
#pragma unroll
    for (int ot = 0; ot < 5; ot++) {
        int ob = 80 * w + ot * 16;
        const float* mat; int r0;
        if (ob < 32)      { mat = Wq; r0 = ob; }
        else if (ob < 64) { mat = Wk; r0 = ob - 32; }
        else              { mat = Wv; r0 = ob - 64; }
        wrow[ot] = mat + (size_t)(r0 + l15) * CC + lq * 8;
    }

    __syncthreads();

    const f32x4 zf = {0.f, 0.f, 0.f, 0.f};
    f32x4 acc[5][2];
#pragma unroll
    for (int i = 0; i < 5; i++)
#pragma unroll
        for (int j = 0; j < 2; j++) acc[i][j] = zf;

    const __bf16* xls = &xs[l15 * XROW + lq * 8];

    bf16x8 bcur[2], acur[5], bnxt[2], anxt[5];
#pragma unroll
    for (int nt = 0; nt < 2; nt++) bcur[nt] = *(const bf16x8*)(xls + nt * 16 * XROW);
#pragma unroll
    for (int ot = 0; ot < 5; ot++) {
        f32x4 a0 = *(const f32x4*)(wrow[ot]);
        f32x4 a1 = *(const f32x4*)(wrow[ot] + 4);
        bf16x8 af;
#pragma unroll
        for (int j = 0; j < 4; j++) { af[j] = (__bf16)a0[j]; af[4 + j] = (__bf16)a1[j]; }
        acur[ot] = af;
    }

#pragma unroll
    for (int ks = 0; ks < 8; ks++) {
        if (ks < 7) {
#pragma unroll
            for (int nt = 0; nt < 2; nt++)
                bnxt[nt] = *(const bf16x8*)(xls + nt * 16 * XROW + (ks + 1) * 32);
#pragma unroll
            for (int ot = 0; ot < 5; ot++) {
                f32x4 a0 = *(const f32x4*)(wrow[ot] + (ks + 1) * 32);
                f32x4 a1 = *(const f32x4*)(wrow[ot] + (ks + 1) * 32 + 4);
                bf16x8 af;
#pragma unroll
                for (int j = 0; j < 4; j++) { af[j] = (__bf16)a0[j]; af[4 + j] = (__bf16)a1[j]; }
                anxt[ot] = af;
            }
        }
#pragma unroll
        for (int ot = 0; ot < 5; ot++)
#pragma unroll
            for (int nt = 0; nt < 2; nt++)
                acc[ot][nt] = __builtin_amdgcn_mfma_f32_16x16x32_bf16(acur[ot], bcur[nt], acc[ot][nt], 0, 0, 0);
        if (ks < 7) {
#pragma unroll
            for (int nt = 0; nt < 2; nt++) bcur[nt] = bnxt[nt];
#pragma unroll
            for (int ot = 0; ot < 5; ot++) acur[ot] = anxt[ot];
        }
    }

    __syncthreads();   // all xs reads complete before scr overlays the LDS

    // epilogue: D row o = 80w + ot*16 + lq*4 + r, col n = nt*16 + l15
    // V store layout: vchunk[ct*1024 + kb*512 + (c&31)*16 + (n&15)]
    __bf16* vchunk = vws + (size_t)b * CC * NN + (size_t)(n0 >> 5) * 8192;
#pragma unroll
    for (int ot = 0; ot < 5; ot++) {
        int ob = 80 * w + ot * 16;
#pragma unroll
        for (int nt = 0; nt < 2; nt++) {
#pragma unroll
            for (int r = 0; r < 4; r++) {
                int o = ob + lq * 4 + r;
                int n = nt * 16 + l15;
                float val = acc[ot][nt][r];
                if (ob >= 64) {
                    int c  = o - 64;
                    int ct = c >> 5, c5 = c & 31;
                    vchunk[ct * 1024 + nt * 512 + c5 * 16 + l15] =
                        (__bf16)(val + bv[c]);
                } else if (ob < 32) {
                    scr[o][n] = (val + bq[o]) * QSCALE2;
                } else {
                    scr[o][n] = val + bk[o - 32];
                }
            }
        }
    }
    __syncthreads();
    {
        int n  = tid >> 3;            // 0..31
        int d0 = (tid & 7) * 4;       // 0..28
        bf16x4 qv, kv;
#pragma unroll
        for (int j = 0; j < 4; j++) {
            qv[j] = (__bf16)scr[d0 + j][n];
            kv[j] = (__bf16)scr[32 + d0 + j][n];
        }
        size_t base = ((size_t)b * NN + n0 + n) * DKK + d0;
        *(bf16x4*)&qws[base] = qv;
        *(bf16x4*)&kws[base] = kv;
    }
}

// ---------------------------------------------------------------------------
// Kernel 2: flash attention — 32x32 MFMA, zero-LDS main loop, REGISTER
// software pipeline. Round-8 delta vs R7 (which serialized KQ->exp->swap->PV
// in one iteration and spilled ~18 dwords: WRITE_SIZE 16384->25600 KB):
//  - 1-deep pipeline restored in registers: pfA/pfB ping-pong, hand-unrolled
//    x2 so all pf indices are compile-time (rule #20). PV(ic) consumes the
//    P produced in iteration ic-1 -> PV MFMAs independent of current
//    KQ/exp chain (this was R5's hidden win via the LDS double-buffer).
//  - K prefetch window shrunk to 8 regs (kA0/kA1 reloaded in place right
//    after kq_pack consumes them; L2-resident K, ~200cy, covered by the
//    16-MFMA PV phase) to pay for the extra 16 P registers. Audited
//    steady live-set ~102-118 VGPR; no-spill is the success criterion.
// permlane32_swap P-assembly unchanged (verified correct in R7).
// ---------------------------------------------------------------------------
#define MST 68                     // O-reduce row stride (dwords)

__global__ __launch_bounds__(256, 2) void attn_kernel(
    const __bf16* __restrict__ qb, const __bf16* __restrict__ kb,
    const __bf16* __restrict__ vt, const float* __restrict__ x,
    float* __restrict__ out)
{
    // [0, 34816)       Ored (epilogue): 4 waves x 32 x MST fp32
    // [34816, 35840)   Ls[4][64]
    // [35840, 36096)   Linv[64]
    __shared__ __align__(16) unsigned char smem[36096];
    const int tid = threadIdx.x;
    const int w   = tid >> 6;
    const int l   = tid & 63;
    const int m31 = l & 31;           // MFMA col lane (m / A-row)
    const int hi  = l >> 5;           // k-half lane
    float* Ls   = (float*)(smem + 34816);
    float* Linv = (float*)(smem + 35840);

    // XCD swizzle: batch pinned to an XCD pair -> K/V/Q stay L2-resident
    const int beta = blockIdx.x;
    const int b    = (beta >> 1) & 3;
    const int ch   = (beta >> 3) & 1;                        // c-half
    const int mt64 = ((beta >> 4) << 1) | (beta & 1);        // 0..63
    const int m0   = mt64 * 64;

    const __bf16* qbb = qb + (size_t)b * NN * DKK;
    const __bf16* kbb = kb + (size_t)b * NN * DKK;
    const __bf16* vtb = vt + (size_t)b * CC * NN;

    // Q B-frags: qa[mt][kk]: Q[m0+mt*32+m31][kk*16 + hi*8 + j]
    bf16x8 qa[2][2];
#pragma unroll
    for (int mt = 0; mt < 2; mt++)
#pragma unroll
        for (int kk = 0; kk < 2; kk++)
            qa[mt][kk] = *(const bf16x8*)(qbb + (size_t)(m0 + mt * 32 + m31) * DKK + kk * 16 + hi * 8);

    // K A-frag strip: K[w*32 + m31 + 128*ic][hi*8 + j (+16 for kA1)]
    const __bf16* kstrip = kbb + (size_t)(w * 32 + m31) * DKK + hi * 8;
    // V A-frag strip: tile (chunk=ic*4+w, ct, kb), lane (c=m31, n=hi*8+j)
    const __bf16* vstrip = vtb + (size_t)w * 8192 + (size_t)ch * 4096
                               + m31 * 16 + hi * 8;

    const f32x16 zf16 = {0.f,0.f,0.f,0.f,0.f,0.f,0.f,0.f,
                         0.f,0.f,0.f,0.f,0.f,0.f,0.f,0.f};
    f32x16 acc[4][2];                 // [ct][mt] = 128 AGPR
#pragma unroll
    for (int ct = 0; ct < 4; ct++)
#pragma unroll
        for (int mt = 0; mt < 2; mt++) acc[ct][mt] = zf16;
    float lacc[2] = {0.f, 0.f};

    // KQ + exp + in-register P assembly (permlane32_swap, R7-verified).
    // e reg g*4+t -> n = g*8 + 4*hi + t. Pack group g to 2 u32; swap
    // (g_even, g_odd) across the hi halves: result = pf[mt][g>>1].
    union PU { unsigned u[4]; bf16x8 v; };
    auto kq_pack = [&](bf16x8 kA0, bf16x8 kA1, bf16x8 (&pf)[2][2]) {
#pragma unroll
        for (int mt = 0; mt < 2; mt++) {
            f32x16 e = __builtin_amdgcn_mfma_f32_32x32x16_bf16(kA0, qa[mt][0], zf16, 0, 0, 0);
            e = __builtin_amdgcn_mfma_f32_32x32x16_bf16(kA1, qa[mt][1], e, 0, 0, 0);
            float s = 0.f;
            unsigned g[4][2];
#pragma unroll
            for (int gi = 0; gi < 4; gi++) {
                bf16x4 pb;
#pragma unroll
                for (int t = 0; t < 4; t++) {
                    float v = __builtin_amdgcn_exp2f(e[4 * gi + t]);
                    s += v; pb[t] = (__bf16)v;
                }
                PU tu; *(bf16x4*)tu.u = pb;
                g[gi][0] = tu.u[0]; g[gi][1] = tu.u[1];
            }
            lacc[mt] += s;
#pragma unroll
            for (int kk = 0; kk < 2; kk++) {
                PU r;
#pragma unroll
                for (int wi = 0; wi < 2; wi++) {
                    auto sw = __builtin_amdgcn_permlane32_swap(
                        (int)g[kk * 2][wi], (int)g[kk * 2 + 1][wi], false, false);
                    r.u[wi]     = (unsigned)sw[0];
                    r.u[2 + wi] = (unsigned)sw[1];
                }
                pf[mt][kk] = r.v;
            }
        }
    };

    // PV(ic): vA (kb0) preloaded by caller; vB (kb1) loaded here with the
    // 8 kb0-MFMAs as latency cover.
    auto pv_step = [&](const __bf16* vch, bf16x8 (&pf)[2][2], bf16x8 (&vA)[4]) {
        bf16x8 vB[4];
#pragma unroll
        for (int ct = 0; ct < 4; ct++)
            vB[ct] = *(const bf16x8*)(vch + ct * 1024 + 512);
        __builtin_amdgcn_s_setprio(1);
#pragma unroll
        for (int ct = 0; ct < 4; ct++)
#pragma unroll
            for (int mt = 0; mt < 2; mt++) {
                acc[ct][mt] = __builtin_amdgcn_mfma_f32_32x32x16_bf16(vA[ct], pf[mt][0], acc[ct][mt], 0, 0, 0);
                acc[ct][mt] = __builtin_amdgcn_mfma_f32_32x32x16_bf16(vB[ct], pf[mt][1], acc[ct][mt], 0, 0, 0);
            }
        __builtin_amdgcn_s_setprio(0);
    };

    // ---- prologue: P(0) -> pfA; K(1) in kA ----
    bf16x8 pfA[2][2], pfB[2][2];
    bf16x8 kA0 = *(const bf16x8*)kstrip;
    bf16x8 kA1 = *(const bf16x8*)(kstrip + 16);
    kq_pack(kA0, kA1, pfA);
    kA0 = *(const bf16x8*)(kstrip + (size_t)128 * DKK);
    kA1 = *(const bf16x8*)(kstrip + (size_t)128 * DKK + 16);

    // ---- main loop: zero barriers, zero LDS; hand-unrolled x2 so the
    //      pfA/pfB ping-pong uses only compile-time register indices ----
#pragma unroll 1
    for (int icp = 0; icp < 16; icp++) {
        const int ic0 = icp * 2;
        {   // even: PV(ic0) w/ pfA; KQ(ic0+1) -> pfB
            const __bf16* vch = vstrip + (size_t)ic0 * 32768;
            bf16x8 vA[4];
#pragma unroll
            for (int ct = 0; ct < 4; ct++)
                vA[ct] = *(const bf16x8*)(vch + ct * 1024);
            kq_pack(kA0, kA1, pfB);
            // reload kA in place: K(ic0+2); at icp=15 reads adjacent ws
            // region (never consumed) — harmless
            kA0 = *(const bf16x8*)(kstrip + (size_t)(ic0 + 2) * 128 * DKK);
            kA1 = *(const bf16x8*)(kstrip + (size_t)(ic0 + 2) * 128 * DKK + 16);
            pv_step(vch, pfA, vA);
        }
        {   // odd: PV(ic0+1) w/ pfB; KQ(ic0+2) -> pfA (skip on last pair)
            const __bf16* vch = vstrip + (size_t)(ic0 + 1) * 32768;
            bf16x8 vA[4];
#pragma unroll
            for (int ct = 0; ct < 4; ct++)
                vA[ct] = *(const bf16x8*)(vch + ct * 1024);
            if (icp < 15) {
                kq_pack(kA0, kA1, pfA);
                kA0 = *(const bf16x8*)(kstrip + (size_t)(ic0 + 3) * 128 * DKK);
                kA1 = *(const bf16x8*)(kstrip + (size_t)(ic0 + 3) * 128 * DKK + 16);
            }
            pv_step(vch, pfB, vA);
        }
    }

    // ---- l: intra-wave reduce (lanes l and l^32 share m), publish ----
#pragma unroll
    for (int mt = 0; mt < 2; mt++) lacc[mt] += __shfl_xor(lacc[mt], 32, 64);
    if (hi == 0) {
#pragma unroll
        for (int mt = 0; mt < 2; mt++) Ls[w * 64 + mt * 32 + m31] = lacc[mt];
    }
    __syncthreads();
    if (tid < 64)
        Linv[tid] = 1.0f / (Ls[tid] + Ls[64 + tid] + Ls[128 + tid] + Ls[192 + tid]);

    // ---- epilogue: cross-wave O reduce, one 32-c quarter per ct ----
    // acc[ct][mt][reg]: c = ch*128 + ct*32 + crow, crow=(reg&3)+8(reg>>2)+4hi;
    // m = mt*32 + m31.
    float* Ored = (float*)smem + w * (32 * MST);
#pragma unroll
    for (int q = 0; q < 4; q++) {
        if (q > 0) __syncthreads();       // prior quarter's reads done
#pragma unroll
        for (int mt = 0; mt < 2; mt++)
#pragma unroll
            for (int reg = 0; reg < 16; reg++) {
                int crow = (reg & 3) + 8 * (reg >> 2) + 4 * hi;
                Ored[crow * MST + mt * 32 + m31] = acc[q][mt][reg];
            }
        __syncthreads();
        // sum 4 wave-partials, normalize, residual, store
        const int cl  = tid >> 3;         // 0..31 (c within quarter)
        const int mi0 = (tid & 7) * 8;    // m offset
        const float* Ob = (const float*)smem + cl * MST;
#pragma unroll
        for (int j = 0; j < 2; j++) {
            int mi = mi0 + 4 * j;
            f32x4 s = *(const f32x4*)&Ob[mi];
            s = s + *(const f32x4*)&Ob[1 * (32 * MST) + mi];
            s = s + *(const f32x4*)&Ob[2 * (32 * MST) + mi];
            s = s + *(const f32x4*)&Ob[3 * (32 * MST) + mi];
            f32x4 li = *(const f32x4*)&Linv[mi];
            int c = ch * 128 + q * 32 + cl;
            size_t gi = ((size_t)(b * CC + c)) * NN + m0 + mi;
            f32x4 xr = *(const f32x4*)&x[gi];
            *(f32x4*)&out[gi] = s * li + xr;
        }
    }
}

extern "C" void kernel_launch(void* const* d_in, const int* in_sizes, int n_in,
                              void* d_out, int out_size, void* d_ws, size_t ws_size,
                              hipStream_t stream) {
    const float* x  = (const float*)d_in[0];
    const float* Wq = (const float*)d_in[1];
    const float* bq = (const float*)d_in[2];
    const float* Wk = (const float*)d_in[3];
    const float* bk = (const float*)d_in[4];
    const float* Wv = (const float*)d_in[5];
    const float* bv = (const float*)d_in[6];
    float* out = (float*)d_out;

    __bf16* qws = (__bf16*)d_ws;                       // B*N*32
    __bf16* kws = qws + (size_t)BB * NN * DKK;         // B*N*32
    __bf16* vws = kws + (size_t)BB * NN * DKK;         // B*C*N (tiled)

    qkv2_kernel<<<dim3(128, BB), 256, 0, stream>>>(x, Wq, Wk, Wv, bq, bk, bv,
                                                   qws, kws, vws);
    attn_kernel<<<dim3(512), 256, 0, stream>>>(qws, kws, vws, x, out);
}